// Round 3
// baseline (160.414 us; speedup 1.0000x reference)
//
#include <hip/hip_runtime.h>
#include <math.h>

namespace {

typedef __attribute__((ext_vector_type(8))) __fp16 f16x8;
typedef __attribute__((ext_vector_type(4))) float f32x4;

constexpr int IN_DIM = 128;
constexpr int EFF    = 130 * 16;   // W1 node stride (floats)
constexpr int NODES  = 255;
constexpr int TS     = 32;         // R18: samples per block (2 MFMA N-tiles)
constexpr int BLOCK  = 256;        // 4 waves (256-thread blocks co-reside; 512 don't)
constexpr int NC     = 10;

// ---- prep: W1[:, :128, :] -> MFMA fragment layout, fp16 (single product) ----
// frag element (n, t, lane l, j): W[k = t*32 + (l>>4)*8 + j][hid = l&15]
__global__ __launch_bounds__(256) void prep_w1(const float* __restrict__ W1,
                                               f16x8* __restrict__ wfrag) {
    __shared__ float xs[IN_DIM * 16];      // 8 KB: rows 0..127 of this node
    const int n = blockIdx.x, tid = threadIdx.x;
    const float4* src = (const float4*)(W1 + (size_t)n * EFF);
    ((float4*)xs)[tid]       = src[tid];
    ((float4*)xs)[tid + 256] = src[tid + 256];
    __syncthreads();
    const int l = tid & 63, t = tid >> 6;
    const int k0 = t * 32 + (l >> 4) * 8, hid = l & 15;
    f16x8 hv;
    #pragma unroll
    for (int j = 0; j < 8; ++j)
        hv[j] = (__fp16)xs[(k0 + j) * 16 + hid];   // RNE
    wfrag[(n * 4 + t) * 64 + l] = hv;
}

__device__ __forceinline__ void loadW(const f16x8* __restrict__ wfrag, int n, int l,
                                      f16x8 (&w)[4]) {
    const f16x8* wp = wfrag + (size_t)n * 256 + l;
    #pragma unroll
    for (int t = 0; t < 4; ++t) w[t] = wp[t * 64];
}

#define COMP4(v, r) ((r == 0) ? v.x : (r == 1) ? v.y : (r == 2) ? v.z : v.w)

// Paired epilogue: 4 score streams = {node A, node B} x {mt 0, mt 1}.
// After the 2 shfl reductions every lane has all 4 full hid-sums; the
// lane-select maps lane l -> node (quad>>1), sample (quad&1)*16+col = l&31.
__device__ __forceinline__ float epi_pair(
    const f32x4 (&accA)[2], const f32x4 (&accB)[2],
    const float4& w2A, const float4& w2B,
    const float4& wpA, const float4& wpB,
    const float4& wgA, const float4& wgB,
    const float (&par)[2], const float (&gp)[2],
    float b2A, float b2B, int quad)
{
    float sc0 = 0.f, sc1 = 0.f, sc2 = 0.f, sc3 = 0.f;
    #pragma unroll
    for (int r = 0; r < 4; ++r) {
        const float wpAr = COMP4(wpA, r), wpBr = COMP4(wpB, r);
        const float wgAr = COMP4(wgA, r), wgBr = COMP4(wgB, r);
        const float w2Ar = COMP4(w2A, r), w2Br = COMP4(w2B, r);
        const float hA0 = fmaf(par[0], wpAr, fmaf(gp[0], wgAr, accA[0][r]));
        const float hA1 = fmaf(par[1], wpAr, fmaf(gp[1], wgAr, accA[1][r]));
        const float hB0 = fmaf(par[0], wpBr, fmaf(gp[0], wgBr, accB[0][r]));
        const float hB1 = fmaf(par[1], wpBr, fmaf(gp[1], wgBr, accB[1][r]));
        sc0 = fmaf(fmaxf(hA0, 0.0f), w2Ar, sc0);
        sc1 = fmaf(fmaxf(hA1, 0.0f), w2Ar, sc1);
        sc2 = fmaf(fmaxf(hB0, 0.0f), w2Br, sc2);
        sc3 = fmaf(fmaxf(hB1, 0.0f), w2Br, sc3);
    }
    sc0 += __shfl_xor(sc0, 16); sc0 += __shfl_xor(sc0, 32);
    sc1 += __shfl_xor(sc1, 16); sc1 += __shfl_xor(sc1, 32);
    sc2 += __shfl_xor(sc2, 16); sc2 += __shfl_xor(sc2, 32);
    sc3 += __shfl_xor(sc3, 16); sc3 += __shfl_xor(sc3, 32);
    const float sa = (quad & 1) ? sc1 : sc0;
    const float sb = (quad & 1) ? sc3 : sc2;
    return ((quad & 2) ? sb : sa) + ((quad & 2) ? b2B : b2A);
}

// Single-node epilogue for depths 0..2 (quads 2,3 compute redundant copies).
__device__ __forceinline__ float epi_single(
    const f32x4 (&acc)[2], const float4& w2q, const float4& wpq, const float4& wgq,
    const float (&par)[2], const float (&gp)[2], float b2v, int quad)
{
    float sc0 = 0.f, sc1 = 0.f;
    #pragma unroll
    for (int r = 0; r < 4; ++r) {
        const float wpr = COMP4(wpq, r), wgr = COMP4(wgq, r), w2r = COMP4(w2q, r);
        const float h0 = fmaf(par[0], wpr, fmaf(gp[0], wgr, acc[0][r]));
        const float h1 = fmaf(par[1], wpr, fmaf(gp[1], wgr, acc[1][r]));
        sc0 = fmaf(fmaxf(h0, 0.0f), w2r, sc0);
        sc1 = fmaf(fmaxf(h1, 0.0f), w2r, sc1);
    }
    sc0 += __shfl_xor(sc0, 16); sc0 += __shfl_xor(sc0, 32);
    sc1 += __shfl_xor(sc1, 16); sc1 += __shfl_xor(sc1, 32);
    return ((quad & 1) ? sc1 : sc0) + b2v;
}

// ---- main fused tree kernel ----
// R18: TS=32, 1024 blocks of 4 waves -> 4 blocks/CU schedulable (grid was the
// occupancy wall: at TS=64 only 2 blocks/CU EXIST). LDS 31.9 KB (5 fit).
// To avoid the lane-redundancy tax of 32-sample tiles, depths >=3 process a
// NODE PAIR (2pl, 2pl+1) per iteration: quads 0/1 carry node A, quads 2/3
// node B -> per-iteration cost identical to R15's single-node TS=64 iteration,
// per-wave serial path HALVES (~34 iters vs ~65), total work unchanged.
// Pair members share parent (pl) and grandparent (pl>>1) -> par/gp LDS reads
// halve. Node ownership ranges match R15 -> same 2-barrier structure (after
// d=0, d=1); everything d>=2 is wave-local. Pipeline flows across depth
// boundaries for d=3..6 (prev epilogue step precedes current reads).
__global__ __launch_bounds__(BLOCK) __attribute__((amdgpu_waves_per_eu(2)))
void tree_mfma(
    const float* __restrict__ x, const float* __restrict__ path_prob,
    const float* __restrict__ W1, const float* __restrict__ b1,
    const float* __restrict__ w2, const float* __restrict__ b2,
    const float* __restrict__ leaf_logits,
    const f16x8* __restrict__ wfrag,
    float* __restrict__ out)
{
    __shared__ float pp[128][TS];          // 16 KB: path probs
    __shared__ float scbuf[127][TS];       // 15.875 KB: depth-d scores at row (2^d - 1)

    const int tid  = threadIdx.x;
    const int wv   = tid >> 6, l = tid & 63;
    const int quad = l >> 4,   col = l & 15;
    const int sl   = l & 31;               // sample index of this lane
    const int nodeIdx = quad >> 1;         // 0: lanes 0-31 (node A), 1: node B
    const int s0   = blockIdx.x * TS;

    if (tid < TS) pp[0][tid] = path_prob[s0 + tid];

    // x fragments (fp16): B operand B[k = t*32+quad*8+j][col], samples mt*16+col
    f16x8 xh[4][2];
    #pragma unroll
    for (int t = 0; t < 4; ++t)
        #pragma unroll
        for (int mt = 0; mt < 2; ++mt) {
            const float* xp = x + (size_t)(s0 + mt * 16 + col) * IN_DIM + t * 32 + quad * 8;
            float4 v0 = ((const float4*)xp)[0];
            float4 v1 = ((const float4*)xp)[1];
            float vv[8] = {v0.x, v0.y, v0.z, v0.w, v1.x, v1.y, v1.z, v1.w};
            f16x8 hv;
            #pragma unroll
            for (int j = 0; j < 8; ++j) hv[j] = (__fp16)vv[j];
            xh[t][mt] = hv;
        }

    // ---------------- phase A: depths 0..2, single node per wave ----------------
    for (int d = 0; d < 3; ++d) {
        const int nd = 1 << d;
        const int stride = 128 >> d, half = 64 >> d;
        if (wv < nd) {
            const int n = nd - 1 + wv;
            f16x8 w[4];
            loadW(wfrag, n, l, w);
            const float4 b1q = ((const float4*)(b1 + n * 16))[quad];
            const float4 w2q = ((const float4*)(w2 + n * 16))[quad];
            const float4 wpq = ((const float4*)(W1 + (size_t)n * EFF + 128 * 16))[quad];
            const float4 wgq = ((const float4*)(W1 + (size_t)n * EFF + 129 * 16))[quad];
            const float  b2v = b2[n];
            float par[2], gp[2];
            #pragma unroll
            for (int mt = 0; mt < 2; ++mt) {
                const int scol = mt * 16 + col;
                par[mt] = (d >= 1) ? scbuf[(nd >> 1) - 1 + (wv >> 1)][scol] : 0.0f;
                gp[mt]  = (d >= 2) ? scbuf[(nd >> 2) - 1 + (wv >> 2)][scol] : 0.0f;
            }
            const int   slot = wv * stride;
            const float ppar = pp[slot][sl];

            f32x4 binit = {b1q.x, b1q.y, b1q.z, b1q.w};
            f32x4 acc[2] = {binit, binit};
            #pragma unroll
            for (int t = 0; t < 4; ++t) {
                acc[0] = __builtin_amdgcn_mfma_f32_16x16x32_f16(w[t], xh[t][0], acc[0], 0, 0, 0);
                acc[1] = __builtin_amdgcn_mfma_f32_16x16x32_f16(w[t], xh[t][1], acc[1], 0, 0, 0);
            }
            const float sv = epi_single(acc, w2q, wpq, wgq, par, gp, b2v, quad);
            if (l < 32) {
                scbuf[nd - 1 + wv][sl] = sv;
                const float p = 1.0f / (1.0f + __expf(-sv));
                pp[slot][sl]        = ppar * p;
                pp[slot + half][sl] = ppar * (1.0f - p);
            }
        }
        if (d < 2) __syncthreads();
    }

    // ---------------- phase B: depths 3..6, paired, pipelined across depths ----------------
    bool havePrev = false;
    f32x4  pAccA[2], pAccB[2];
    float4 pW2A, pW2B, pWpA, pWpB, pWgA, pWgB;
    float  pB2A = 0.f, pB2B = 0.f, pPpar = 0.f;
    float  pPar[2], pGp[2];
    int    pScwAbs = 0, pSlotBase = 0, pStride = 0, pHalf = 0;

    for (int d = 3; d < 7; ++d) {
        const int nd = 1 << d;
        const int stride = 128 >> d, half = 64 >> d;
        const int scWo = nd - 1, scPo = (nd >> 1) - 1, scP2o = (nd >> 2) - 1;
        const int plo = wv * (nd >> 3), phi = plo + (nd >> 3);
        for (int pl = plo; pl < phi; ++pl) {
            const int nA = nd - 1 + 2 * pl, nB = nA + 1;

            // (1) issue this pair's W + b1 loads
            f16x8 wA[4], wB[4];
            loadW(wfrag, nA, l, wA);
            loadW(wfrag, nB, l, wB);
            const float4 b1A = ((const float4*)(b1 + nA * 16))[quad];
            const float4 b1B = ((const float4*)(b1 + nB * 16))[quad];

            // (2) overlapped epilogue of previous pair
            if (havePrev) {
                const float sv = epi_pair(pAccA, pAccB, pW2A, pW2B, pWpA, pWpB,
                                          pWgA, pWgB, pPar, pGp, pB2A, pB2B, quad);
                scbuf[pScwAbs + nodeIdx][sl] = sv;
                const float p = 1.0f / (1.0f + __expf(-sv));
                const int slot = pSlotBase + nodeIdx * pStride;
                pp[slot][sl]         = pPpar * p;
                pp[slot + pHalf][sl] = pPpar * (1.0f - p);
            }

            // (3) this pair's epilogue scalars (consumed NEXT iteration)
            const float4 w2A = ((const float4*)(w2 + nA * 16))[quad];
            const float4 w2B = ((const float4*)(w2 + nB * 16))[quad];
            const float4 wpA = ((const float4*)(W1 + (size_t)nA * EFF + 128 * 16))[quad];
            const float4 wpB = ((const float4*)(W1 + (size_t)nB * EFF + 128 * 16))[quad];
            const float4 wgA = ((const float4*)(W1 + (size_t)nA * EFF + 129 * 16))[quad];
            const float4 wgB = ((const float4*)(W1 + (size_t)nB * EFF + 129 * 16))[quad];
            const float  b2A = b2[nA], b2B = b2[nB];
            float par[2], gp[2];
            #pragma unroll
            for (int mt = 0; mt < 2; ++mt) {
                const int scol = mt * 16 + col;
                par[mt] = scbuf[scPo + pl][scol];
                gp[mt]  = scbuf[scP2o + (pl >> 1)][scol];
            }
            const float ppar = pp[(2 * pl + nodeIdx) * stride][sl];

            // (4) MFMA pair into fresh accumulators (bias folded into init)
            f32x4 binitA = {b1A.x, b1A.y, b1A.z, b1A.w};
            f32x4 binitB = {b1B.x, b1B.y, b1B.z, b1B.w};
            f32x4 accA[2] = {binitA, binitA};
            f32x4 accB[2] = {binitB, binitB};
            #pragma unroll
            for (int t = 0; t < 4; ++t) {
                accA[0] = __builtin_amdgcn_mfma_f32_16x16x32_f16(wA[t], xh[t][0], accA[0], 0, 0, 0);
                accA[1] = __builtin_amdgcn_mfma_f32_16x16x32_f16(wA[t], xh[t][1], accA[1], 0, 0, 0);
                accB[0] = __builtin_amdgcn_mfma_f32_16x16x32_f16(wB[t], xh[t][0], accB[0], 0, 0, 0);
                accB[1] = __builtin_amdgcn_mfma_f32_16x16x32_f16(wB[t], xh[t][1], accB[1], 0, 0, 0);
            }

            // (5) carry state
            pAccA[0] = accA[0]; pAccA[1] = accA[1];
            pAccB[0] = accB[0]; pAccB[1] = accB[1];
            pW2A = w2A; pW2B = w2B; pWpA = wpA; pWpB = wpB; pWgA = wgA; pWgB = wgB;
            pB2A = b2A; pB2B = b2B; pPpar = ppar;
            pPar[0] = par[0]; pPar[1] = par[1]; pGp[0] = gp[0]; pGp[1] = gp[1];
            pScwAbs = scWo + 2 * pl; pSlotBase = 2 * pl * stride;
            pStride = stride; pHalf = half;
            havePrev = true;
        }
    }
    // drain phase B (last d=6 pair)
    if (havePrev) {
        const float sv = epi_pair(pAccA, pAccB, pW2A, pW2B, pWpA, pWpB,
                                  pWgA, pWgB, pPar, pGp, pB2A, pB2B, quad);
        scbuf[pScwAbs + nodeIdx][sl] = sv;
        const float p = 1.0f / (1.0f + __expf(-sv));
        const int slot = pSlotBase + nodeIdx * pStride;
        pp[slot][sl]         = pPpar * p;
        pp[slot + pHalf][sl] = pPpar * (1.0f - p);
    }

    // ---------------- phase C: depth 7, paired leaf-mixture fold (wave-local) ----------------
    float oacc[NC];
    #pragma unroll
    for (int c = 0; c < NC; ++c) oacc[c] = 0.0f;
    {
        bool hp = false;
        int  pPl = 0;
        const int plo = wv * 16, phi = plo + 16;
        for (int pl = plo; pl < phi; ++pl) {
            const int nA = 127 + 2 * pl, nB = nA + 1;

            f16x8 wA[4], wB[4];
            loadW(wfrag, nA, l, wA);
            loadW(wfrag, nB, l, wB);
            const float4 b1A = ((const float4*)(b1 + nA * 16))[quad];
            const float4 b1B = ((const float4*)(b1 + nB * 16))[quad];

            if (hp) {
                const float sv = epi_pair(pAccA, pAccB, pW2A, pW2B, pWpA, pWpB,
                                          pWgA, pWgB, pPar, pGp, pB2A, pB2B, quad);
                const float p  = 1.0f / (1.0f + __expf(-sv));
                const float pL = pPpar * p;
                const float pR = pPpar * (1.0f - p);
                const int   nid = 2 * pPl + nodeIdx;          // internal node id at d=7
                const float* llp = leaf_logits + (size_t)(2 * nid) * NC;
                #pragma unroll
                for (int c = 0; c < NC; ++c)
                    oacc[c] = fmaf(pL, llp[c], fmaf(pR, llp[NC + c], oacc[c]));
            }

            const float4 w2A = ((const float4*)(w2 + nA * 16))[quad];
            const float4 w2B = ((const float4*)(w2 + nB * 16))[quad];
            const float4 wpA = ((const float4*)(W1 + (size_t)nA * EFF + 128 * 16))[quad];
            const float4 wpB = ((const float4*)(W1 + (size_t)nB * EFF + 128 * 16))[quad];
            const float4 wgA = ((const float4*)(W1 + (size_t)nA * EFF + 129 * 16))[quad];
            const float4 wgB = ((const float4*)(W1 + (size_t)nB * EFF + 129 * 16))[quad];
            const float  b2A = b2[nA], b2B = b2[nB];
            float par[2], gp[2];
            #pragma unroll
            for (int mt = 0; mt < 2; ++mt) {
                const int scol = mt * 16 + col;
                par[mt] = scbuf[63 + pl][scol];
                gp[mt]  = scbuf[31 + (pl >> 1)][scol];
            }
            const float ppar = pp[2 * pl + nodeIdx][sl];      // stride = 1 at d=7

            f32x4 binitA = {b1A.x, b1A.y, b1A.z, b1A.w};
            f32x4 binitB = {b1B.x, b1B.y, b1B.z, b1B.w};
            f32x4 accA[2] = {binitA, binitA};
            f32x4 accB[2] = {binitB, binitB};
            #pragma unroll
            for (int t = 0; t < 4; ++t) {
                accA[0] = __builtin_amdgcn_mfma_f32_16x16x32_f16(wA[t], xh[t][0], accA[0], 0, 0, 0);
                accA[1] = __builtin_amdgcn_mfma_f32_16x16x32_f16(wA[t], xh[t][1], accA[1], 0, 0, 0);
                accB[0] = __builtin_amdgcn_mfma_f32_16x16x32_f16(wB[t], xh[t][0], accB[0], 0, 0, 0);
                accB[1] = __builtin_amdgcn_mfma_f32_16x16x32_f16(wB[t], xh[t][1], accB[1], 0, 0, 0);
            }

            pAccA[0] = accA[0]; pAccA[1] = accA[1];
            pAccB[0] = accB[0]; pAccB[1] = accB[1];
            pW2A = w2A; pW2B = w2B; pWpA = wpA; pWpB = wpB; pWgA = wgA; pWgB = wgB;
            pB2A = b2A; pB2B = b2B; pPpar = ppar;
            pPar[0] = par[0]; pPar[1] = par[1]; pGp[0] = gp[0]; pGp[1] = gp[1];
            pPl = pl;
            hp = true;
        }
        // drain
        if (hp) {
            const float sv = epi_pair(pAccA, pAccB, pW2A, pW2B, pWpA, pWpB,
                                      pWgA, pWgB, pPar, pGp, pB2A, pB2B, quad);
            const float p  = 1.0f / (1.0f + __expf(-sv));
            const float pL = pPpar * p;
            const float pR = pPpar * (1.0f - p);
            const int   nid = 2 * pPl + nodeIdx;
            const float* llp = leaf_logits + (size_t)(2 * nid) * NC;
            #pragma unroll
            for (int c = 0; c < NC; ++c)
                oacc[c] = fmaf(pL, llp[c], fmaf(pR, llp[NC + c], oacc[c]));
        }
    }

    // ---------------- cross-wave out reduction through scbuf ----------------
    // Sample s needs contributions from lanes s and 32+s of all 4 waves.
    __syncthreads();
    {
        float* red = &scbuf[0][0];         // 4*64*10 = 2560 floats <= 127*32 = 4064
        #pragma unroll
        for (int c = 0; c < NC; ++c)
            red[(wv * 64 + l) * NC + c] = oacc[c];
    }
    __syncthreads();
    {
        const float* red = &scbuf[0][0];
        for (int i = tid; i < TS * NC; i += BLOCK) {
            const int s = i / NC, c = i - s * NC;
            float v = 0.0f;
            #pragma unroll
            for (int w = 0; w < 4; ++w)
                v += red[(w * 64 + s) * NC + c] + red[(w * 64 + 32 + s) * NC + c];
            out[(size_t)s0 * NC + i] = v;
        }
    }
}

} // namespace

extern "C" void kernel_launch(void* const* d_in, const int* in_sizes, int n_in,
                              void* d_out, int out_size, void* d_ws, size_t ws_size,
                              hipStream_t stream) {
    const float* x           = (const float*)d_in[0];
    const float* path_prob   = (const float*)d_in[1];
    const float* W1          = (const float*)d_in[2];
    const float* b1          = (const float*)d_in[3];
    const float* w2          = (const float*)d_in[4];
    const float* b2          = (const float*)d_in[5];
    const float* leaf_logits = (const float*)d_in[6];
    float* out = (float*)d_out;

    const int batch = in_sizes[0] / IN_DIM;                // 32768
    f16x8* wfrag = (f16x8*)d_ws;                           // 255*4*64*16B ~= 1.04 MB

    hipLaunchKernelGGL(prep_w1, dim3(NODES), dim3(256), 0, stream, W1, wfrag);
    hipLaunchKernelGGL(tree_mfma, dim3(batch / TS), dim3(BLOCK), 0, stream,
                       x, path_prob, W1, b1, w2, b2, leaf_logits, wfrag, out);
}

// Round 4
// 142.630 us; speedup vs baseline: 1.1247x; 1.1247x over previous
//
#include <hip/hip_runtime.h>
#include <math.h>

namespace {

typedef __attribute__((ext_vector_type(8))) __fp16 f16x8;
typedef __attribute__((ext_vector_type(4))) float f32x4;

constexpr int IN_DIM = 128;
constexpr int EFF    = 130 * 16;   // W1 node stride (floats)
constexpr int NODES  = 255;
constexpr int TS     = 64;         // samples per block (4 MFMA N-tiles per wave)
constexpr int BLOCK  = 256;
constexpr int NC     = 10;

// ---- prep: W1[:, :128, :] -> MFMA fragment layout, fp16 (single product) ----
// frag element (n, t, lane l, j): W[k = t*32 + (l>>4)*8 + j][hid = l&15]
__global__ __launch_bounds__(256) void prep_w1(const float* __restrict__ W1,
                                               f16x8* __restrict__ wfrag) {
    __shared__ float xs[IN_DIM * 16];      // 8 KB: rows 0..127 of this node
    const int n = blockIdx.x, tid = threadIdx.x;
    const float4* src = (const float4*)(W1 + (size_t)n * EFF);
    ((float4*)xs)[tid]       = src[tid];
    ((float4*)xs)[tid + 256] = src[tid + 256];
    __syncthreads();
    const int l = tid & 63, t = tid >> 6;
    const int k0 = t * 32 + (l >> 4) * 8, hid = l & 15;
    f16x8 hv;
    #pragma unroll
    for (int j = 0; j < 8; ++j)
        hv[j] = (__fp16)xs[(k0 + j) * 16 + hid];   // RNE
    wfrag[(n * 4 + t) * 64 + l] = hv;
}

__device__ __forceinline__ void loadW(const f16x8* __restrict__ wfrag, int n, int l,
                                      f16x8 (&w)[4]) {
    const f16x8* wp = wfrag + (size_t)n * 256 + l;
    #pragma unroll
    for (int t = 0; t < 4; ++t) w[t] = wp[t * 64];
}

__device__ __forceinline__ void mfma16(const f16x8 (&w)[4], const f16x8 (&xh)[4][4],
                                       f32x4 (&acc)[4]) {
    #pragma unroll
    for (int t = 0; t < 4; ++t)
        #pragma unroll
        for (int mt = 0; mt < 4; ++mt)
            acc[mt] = __builtin_amdgcn_mfma_f32_16x16x32_f16(w[t], xh[t][mt], acc[mt], 0, 0, 0);
}

// combine + hid-reduce (3 in-lane adds + 2 shfls per mt) + lane-select
__device__ __forceinline__ float epilogue_score(
    const f32x4 (&acc)[4], const float4& w2q, const float4& wpq, const float4& wgq,
    const float (&par)[4], const float (&gp)[4], float b2v, int quad)
{
    float score01[4];
    #pragma unroll
    for (int mt = 0; mt < 4; ++mt) {
        float ts = 0.0f;
        #pragma unroll
        for (int r = 0; r < 4; ++r) {
            const float wpr = (r == 0) ? wpq.x : (r == 1) ? wpq.y : (r == 2) ? wpq.z : wpq.w;
            const float wgr = (r == 0) ? wgq.x : (r == 1) ? wgq.y : (r == 2) ? wgq.z : wgq.w;
            const float w2r = (r == 0) ? w2q.x : (r == 1) ? w2q.y : (r == 2) ? w2q.z : w2q.w;
            const float h = fmaf(par[mt], wpr, fmaf(gp[mt], wgr, acc[mt][r]));
            ts = fmaf(fmaxf(h, 0.0f), w2r, ts);
        }
        ts += __shfl_xor(ts, 16);
        ts += __shfl_xor(ts, 32);
        score01[mt] = ts;
    }
    const float sa = (quad & 1) ? score01[1] : score01[0];
    const float sb = (quad & 1) ? score01[3] : score01[2];
    return ((quad & 2) ? sb : sa) + b2v;
}

// ---- main fused tree kernel ----
// R19: back to the proven R15 structure (TS=64, 4 waves, 2 barriers, 73.6us).
// Rounds 16-18 proved the machine pins at ~8 waves/CU for every grid/block
// shape tried -> occupancy is not the lever. The remaining all-wave stall is
// short load->use slack: loadW (4x dwordx4 from L2, ~200-400cy) and b1 were
// issued in step (1) and consumed by the MFMA burst in step (4) of the SAME
// iteration (~150cy apart); leaf-logit rows were loaded INSIDE the d7
// epilogue with zero slack. R19 software-pipelines these one iteration ahead
// (like the epilogue scalars already were): preload the depth's first node,
// prefetch node n+1 during iteration n, carry in registers. Arithmetic is
// bit-identical to R15.
__global__ __launch_bounds__(BLOCK) __attribute__((amdgpu_waves_per_eu(2)))
void tree_mfma(
    const float* __restrict__ x, const float* __restrict__ path_prob,
    const float* __restrict__ W1, const float* __restrict__ b1,
    const float* __restrict__ w2, const float* __restrict__ b2,
    const float* __restrict__ leaf_logits,
    const f16x8* __restrict__ wfrag,
    float* __restrict__ out)
{
    __shared__ float pp[128][TS];          // 32 KB: path probs, depths 0..6 only
    __shared__ float scbuf[127][TS];       // 31.75 KB: depth-d scores at row (2^d - 1)

    const int tid  = threadIdx.x;
    const int wv   = tid >> 6, l = tid & 63;
    const int quad = l >> 4,   col = l & 15;
    const int s0   = blockIdx.x * TS;

    if (tid < TS) pp[0][tid] = path_prob[s0 + tid];

    // x fragments (fp16): B operand B[k = t*32+quad*8+j][col]
    f16x8 xh[4][4];
    #pragma unroll
    for (int t = 0; t < 4; ++t)
        #pragma unroll
        for (int mt = 0; mt < 4; ++mt) {
            const float* xp = x + (size_t)(s0 + mt * 16 + col) * IN_DIM + t * 32 + quad * 8;
            float4 v0 = ((const float4*)xp)[0];
            float4 v1 = ((const float4*)xp)[1];
            float vv[8] = {v0.x, v0.y, v0.z, v0.w, v1.x, v1.y, v1.z, v1.w};
            f16x8 hv;
            #pragma unroll
            for (int j = 0; j < 8; ++j) hv[j] = (__fp16)vv[j];
            xh[t][mt] = hv;
        }

    // ---------------- depths 0..6: software-pipelined, subtree-owned ----------------
    for (int d = 0; d < 7; ++d) {
        const int nd = 1 << d;
        float (*scW)[TS]  = (float(*)[TS])&scbuf[nd - 1][0];
        float (*scP)[TS]  = (float(*)[TS])&scbuf[(nd >> 1) - 1][0];   // d-1 region (d>=1)
        float (*scP2)[TS] = (float(*)[TS])&scbuf[(nd >> 2) - 1][0];   // d-2 region (d>=2)
        const int stride = 128 >> d, half = 64 >> d;

        int nlo, nhi;
        if (d >= 2) { nlo = wv * (nd >> 2); nhi = nlo + (nd >> 2); }
        else        { nlo = wv; nhi = (wv < nd) ? wv + 1 : wv; }      // d<2: waves 0..nd-1

        bool havePrev = false;
        f32x4 accP[4];
        float4 p_w2q, p_wpq, p_wgq;
        float  p_b2v = 0.f, p_ppar = 0.f;
        float  p_par[4], p_gp[4];
        int    p_slot = 0, p_nl = 0;

        // pipeline head: preload first node's W + b1
        f16x8 wC[4];
        float4 b1C;
        if (nlo < nhi) {
            loadW(wfrag, nd - 1 + nlo, l, wC);
            b1C = ((const float4*)(b1 + (nd - 1 + nlo) * 16))[quad];
        }

        for (int nl = nlo; nl < nhi; ++nl) {
            const int n = nd - 1 + nl;
            const bool hasNext = (nl + 1 < nhi);   // wave-uniform

            // (1) prefetch NEXT node's W + b1 (consumed next iteration)
            f16x8 wN[4];
            float4 b1N;
            if (hasNext) {
                loadW(wfrag, n + 1, l, wN);
                b1N = ((const float4*)(b1 + (n + 1) * 16))[quad];
            }

            // (2) overlapped epilogue of previous node
            if (havePrev) {
                const float sv = epilogue_score(accP, p_w2q, p_wpq, p_wgq, p_par, p_gp, p_b2v, quad);
                scW[p_nl][l] = sv;
                const float p = 1.0f / (1.0f + __expf(-sv));
                pp[p_slot][l]        = p_ppar * p;
                pp[p_slot + half][l] = p_ppar * (1.0f - p);
            }

            // (3) this node's epilogue scalars (consumed NEXT iteration)
            const float4 w2q = ((const float4*)(w2 + n * 16))[quad];
            const float4 wpq = ((const float4*)(W1 + (size_t)n * EFF + 128 * 16))[quad];
            const float4 wgq = ((const float4*)(W1 + (size_t)n * EFF + 129 * 16))[quad];
            const float  b2v = b2[n];
            const int    slot = nl * stride;
            const float  ppar = pp[slot][l];
            float par[4], gp[4];
            #pragma unroll
            for (int mt = 0; mt < 4; ++mt) {
                const int scol = mt * 16 + col;
                par[mt] = (d >= 1) ? scP[nl >> 1][scol] : 0.0f;
                gp[mt]  = (d >= 2) ? scP2[nl >> 2][scol] : 0.0f;
            }

            // (4) MFMA with the PRE-LOADED fragments (full-iteration slack)
            f32x4 binit = {b1C.x, b1C.y, b1C.z, b1C.w};
            f32x4 acc[4] = {binit, binit, binit, binit};
            mfma16(wC, xh, acc);

            // (5) carry state + advance prefetch registers
            #pragma unroll
            for (int mt = 0; mt < 4; ++mt) accP[mt] = acc[mt];
            p_w2q = w2q; p_wpq = wpq; p_wgq = wgq;
            p_b2v = b2v; p_ppar = ppar;
            #pragma unroll
            for (int mt = 0; mt < 4; ++mt) { p_par[mt] = par[mt]; p_gp[mt] = gp[mt]; }
            p_slot = slot; p_nl = nl;
            if (hasNext) {
                #pragma unroll
                for (int t = 0; t < 4; ++t) wC[t] = wN[t];
                b1C = b1N;
            }
            havePrev = true;
        }
        // drain
        if (havePrev) {
            const float sv = epilogue_score(accP, p_w2q, p_wpq, p_wgq, p_par, p_gp, p_b2v, quad);
            scW[p_nl][l] = sv;
            const float p = 1.0f / (1.0f + __expf(-sv));
            pp[p_slot][l]        = p_ppar * p;
            pp[p_slot + half][l] = p_ppar * (1.0f - p);
        }
        // only d0/d1 results are read cross-wave (d>=3 reads are wave-local)
        if (d < 2) __syncthreads();
    }

    // ---------------- depth 7: pipelined fold of leaf mixture (wave-local) ----------------
    float oacc[NC];
    #pragma unroll
    for (int c = 0; c < NC; ++c) oacc[c] = 0.0f;
    {
        float (*scP)[TS]  = (float(*)[TS])&scbuf[63][0];   // d=6 scores
        float (*scP2)[TS] = (float(*)[TS])&scbuf[31][0];   // d=5 scores

        bool havePrev = false;
        f32x4 accP[4];
        float4 p_w2q, p_wpq, p_wgq;
        float  p_b2v = 0.f, p_ppar = 0.f;
        float  p_par[4], p_gp[4];
        float  p_ll0[NC], p_ll1[NC];

        const int nlo = wv * 32, nhi = nlo + 32;

        // pipeline head: preload first node's W + b1
        f16x8 wC[4];
        float4 b1C;
        loadW(wfrag, 127 + nlo, l, wC);
        b1C = ((const float4*)(b1 + (127 + nlo) * 16))[quad];

        for (int nl = nlo; nl < nhi; ++nl) {
            const int n = 127 + nl;
            const bool hasNext = (nl + 1 < nhi);   // wave-uniform

            // (1) prefetch NEXT node's W + b1
            f16x8 wN[4];
            float4 b1N;
            if (hasNext) {
                loadW(wfrag, n + 1, l, wN);
                b1N = ((const float4*)(b1 + (n + 1) * 16))[quad];
            }

            // (2) overlapped epilogue of previous node (leaf rows pre-carried)
            if (havePrev) {
                const float sv = epilogue_score(accP, p_w2q, p_wpq, p_wgq, p_par, p_gp, p_b2v, quad);
                const float p = 1.0f / (1.0f + __expf(-sv));
                const float pL = p_ppar * p;
                const float pR = p_ppar * (1.0f - p);
                #pragma unroll
                for (int c = 0; c < NC; ++c)
                    oacc[c] = fmaf(pL, p_ll0[c], fmaf(pR, p_ll1[c], oacc[c]));
            }

            // (3) this node's epilogue scalars + leaf rows (consumed NEXT iteration)
            const float4 w2q = ((const float4*)(w2 + n * 16))[quad];
            const float4 wpq = ((const float4*)(W1 + (size_t)n * EFF + 128 * 16))[quad];
            const float4 wgq = ((const float4*)(W1 + (size_t)n * EFF + 129 * 16))[quad];
            const float  b2v = b2[n];
            const float  ppar = pp[nl][l];
            float par[4], gp[4];
            #pragma unroll
            for (int mt = 0; mt < 4; ++mt) {
                const int scol = mt * 16 + col;
                par[mt] = scP[nl >> 1][scol];
                gp[mt]  = scP2[nl >> 2][scol];
            }
            const float* lp = leaf_logits + (size_t)(2 * nl) * NC;
            float ll0[NC], ll1[NC];
            #pragma unroll
            for (int c = 0; c < NC; ++c) { ll0[c] = lp[c]; ll1[c] = lp[NC + c]; }

            // (4) MFMA with the PRE-LOADED fragments
            f32x4 binit = {b1C.x, b1C.y, b1C.z, b1C.w};
            f32x4 acc[4] = {binit, binit, binit, binit};
            mfma16(wC, xh, acc);

            // (5) carry state + advance prefetch registers
            #pragma unroll
            for (int mt = 0; mt < 4; ++mt) accP[mt] = acc[mt];
            p_w2q = w2q; p_wpq = wpq; p_wgq = wgq;
            p_b2v = b2v; p_ppar = ppar;
            #pragma unroll
            for (int mt = 0; mt < 4; ++mt) { p_par[mt] = par[mt]; p_gp[mt] = gp[mt]; }
            #pragma unroll
            for (int c = 0; c < NC; ++c) { p_ll0[c] = ll0[c]; p_ll1[c] = ll1[c]; }
            if (hasNext) {
                #pragma unroll
                for (int t = 0; t < 4; ++t) wC[t] = wN[t];
                b1C = b1N;
            }
            havePrev = true;
        }
        // drain
        if (havePrev) {
            const float sv = epilogue_score(accP, p_w2q, p_wpq, p_wgq, p_par, p_gp, p_b2v, quad);
            const float p = 1.0f / (1.0f + __expf(-sv));
            const float pL = p_ppar * p;
            const float pR = p_ppar * (1.0f - p);
            #pragma unroll
            for (int c = 0; c < NC; ++c)
                oacc[c] = fmaf(pL, p_ll0[c], fmaf(pR, p_ll1[c], oacc[c]));
        }
    }

    // ---------------- cross-wave out reduction through scbuf ----------------
    __syncthreads();
    {
        float* red = &scbuf[0][0];         // 4*64*10 = 2560 floats <= 8128
        #pragma unroll
        for (int c = 0; c < NC; ++c)
            red[(wv * 64 + l) * NC + c] = oacc[c];
    }
    __syncthreads();
    {
        const float* red = &scbuf[0][0];
        for (int i = tid; i < TS * NC; i += BLOCK) {
            float v = red[i] + red[640 + i] + red[1280 + i] + red[1920 + i];
            out[(size_t)s0 * NC + i] = v;
        }
    }
}

} // namespace

extern "C" void kernel_launch(void* const* d_in, const int* in_sizes, int n_in,
                              void* d_out, int out_size, void* d_ws, size_t ws_size,
                              hipStream_t stream) {
    const float* x           = (const float*)d_in[0];
    const float* path_prob   = (const float*)d_in[1];
    const float* W1          = (const float*)d_in[2];
    const float* b1          = (const float*)d_in[3];
    const float* w2          = (const float*)d_in[4];
    const float* b2          = (const float*)d_in[5];
    const float* leaf_logits = (const float*)d_in[6];
    float* out = (float*)d_out;

    const int batch = in_sizes[0] / IN_DIM;                // 32768
    f16x8* wfrag = (f16x8*)d_ws;                           // 255*4*64*16B ~= 1.04 MB

    hipLaunchKernelGGL(prep_w1, dim3(NODES), dim3(256), 0, stream, W1, wfrag);
    hipLaunchKernelGGL(tree_mfma, dim3(batch / TS), dim3(BLOCK), 0, stream,
                       x, path_prob, W1, b1, w2, b2, leaf_logits, wfrag, out);
}

// Round 5
// 142.097 us; speedup vs baseline: 1.1289x; 1.0038x over previous
//
#include <hip/hip_runtime.h>
#include <math.h>

namespace {

typedef __attribute__((ext_vector_type(8))) __fp16 f16x8;
typedef __attribute__((ext_vector_type(4))) float f32x4;

constexpr int IN_DIM = 128;
constexpr int EFF    = 130 * 16;   // W1 node stride (floats)
constexpr int NODES  = 255;
constexpr int TS     = 64;         // samples per block (4 MFMA N-tiles per wave)
constexpr int BLOCK  = 256;
constexpr int NC     = 10;

// ---- prep: W1[:, :128, :] -> MFMA fragment layout, fp16 (single product) ----
// frag element (n, t, lane l, j): W[k = t*32 + (l>>4)*8 + j][hid = l&15]
__global__ __launch_bounds__(256) void prep_w1(const float* __restrict__ W1,
                                               f16x8* __restrict__ wfrag) {
    __shared__ float xs[IN_DIM * 16];      // 8 KB: rows 0..127 of this node
    const int n = blockIdx.x, tid = threadIdx.x;
    const float4* src = (const float4*)(W1 + (size_t)n * EFF);
    ((float4*)xs)[tid]       = src[tid];
    ((float4*)xs)[tid + 256] = src[tid + 256];
    __syncthreads();
    const int l = tid & 63, t = tid >> 6;
    const int k0 = t * 32 + (l >> 4) * 8, hid = l & 15;
    f16x8 hv;
    #pragma unroll
    for (int j = 0; j < 8; ++j)
        hv[j] = (__fp16)xs[(k0 + j) * 16 + hid];   // RNE
    wfrag[(n * 4 + t) * 64 + l] = hv;
}

__device__ __forceinline__ void loadW(const f16x8* __restrict__ wfrag, int n, int l,
                                      f16x8 (&w)[4]) {
    const f16x8* wp = wfrag + (size_t)n * 256 + l;
    #pragma unroll
    for (int t = 0; t < 4; ++t) w[t] = wp[t * 64];
}

__device__ __forceinline__ void mfma16(const f16x8 (&w)[4], const f16x8 (&xh)[4][4],
                                       f32x4 (&acc)[4]) {
    #pragma unroll
    for (int t = 0; t < 4; ++t)
        #pragma unroll
        for (int mt = 0; mt < 4; ++mt)
            acc[mt] = __builtin_amdgcn_mfma_f32_16x16x32_f16(w[t], xh[t][mt], acc[mt], 0, 0, 0);
}

#define COMP4(v, r) ((r == 0) ? v.x : (r == 1) ? v.y : (r == 2) ? v.z : v.w)

// combine + hid-reduce. R20: butterfly reduce-scatter — 3 shfl + 3 add + 6
// selects (was 8 shfl + 8 add + 4 selects). xor-32 stage reduces bit1 for
// both bit0-indices, xor-16 stage finishes with a keep/send swap. Only the
// association of the 4-lane sum changes (<=1 ulp on the score).
__device__ __forceinline__ float epi_score(
    const f32x4 (&acc)[4], const float4& w2q, const float4& wpq, const float4& wgq,
    const float (&par)[4], const float (&gp)[4], float b2v, int quad)
{
    float p4[4];
    #pragma unroll
    for (int mt = 0; mt < 4; ++mt) {
        float ts = 0.0f;
        #pragma unroll
        for (int r = 0; r < 4; ++r) {
            const float wpr = COMP4(wpq, r);
            const float wgr = COMP4(wgq, r);
            const float w2r = COMP4(w2q, r);
            const float h = fmaf(par[mt], wpr, fmaf(gp[mt], wgr, acc[mt][r]));
            ts = fmaf(fmaxf(h, 0.0f), w2r, ts);
        }
        p4[mt] = ts;
    }
    const bool hiQ = (quad & 2) != 0;
    const bool loQ = (quad & 1) != 0;
    const float a  = hiQ ? p4[2] : p4[0];   // my-bit1 pair, bit0=0
    const float b  = hiQ ? p4[3] : p4[1];   // my-bit1 pair, bit0=1
    const float sa = hiQ ? p4[0] : p4[2];   // partner-bit1 pair
    const float sb = hiQ ? p4[1] : p4[3];
    const float uA = a + __shfl_xor(sa, 32);
    const float uB = b + __shfl_xor(sb, 32);
    const float k  = loQ ? uB : uA;
    const float s  = loQ ? uA : uB;
    return k + __shfl_xor(s, 16) + b2v;
}

// ---- main fused tree kernel ----
// R20: in-iteration ILP instead of occupancy or prefetch (both disproven,
// R16-R19). Depths >=3 process the node PAIR (2i, 2i+1) per iteration:
// two independent 16-MFMA chains + two independent epilogue chains in one
// basic block -> the scheduler fills each chain's shfl/exp stalls with the
// sibling's arithmetic. No cross-iteration carried state (R19 showed the
// loads are latency-covered by in-iteration work; carried copies cost more
// than they save). Pair shares parent/grandparent -> par/gp LDS reads halve;
// address/loop overhead halves. Ownership identical to R15 -> same 2-barrier
// structure (after d=0, d=1); d>=2 wave-local. Arithmetic order identical
// to R15 except the butterfly reduction's association.
__global__ __launch_bounds__(BLOCK) __attribute__((amdgpu_waves_per_eu(2)))
void tree_mfma(
    const float* __restrict__ x, const float* __restrict__ path_prob,
    const float* __restrict__ W1, const float* __restrict__ b1,
    const float* __restrict__ w2, const float* __restrict__ b2,
    const float* __restrict__ leaf_logits,
    const f16x8* __restrict__ wfrag,
    float* __restrict__ out)
{
    __shared__ float pp[128][TS];          // 32 KB: path probs, depths 0..6 only
    __shared__ float scbuf[127][TS];       // 31.75 KB: depth-d scores at row (2^d - 1)

    const int tid  = threadIdx.x;
    const int wv   = tid >> 6, l = tid & 63;
    const int quad = l >> 4,   col = l & 15;
    const int s0   = blockIdx.x * TS;

    if (tid < TS) pp[0][tid] = path_prob[s0 + tid];

    // x fragments (fp16): B operand B[k = t*32+quad*8+j][col]
    f16x8 xh[4][4];
    #pragma unroll
    for (int t = 0; t < 4; ++t)
        #pragma unroll
        for (int mt = 0; mt < 4; ++mt) {
            const float* xp = x + (size_t)(s0 + mt * 16 + col) * IN_DIM + t * 32 + quad * 8;
            float4 v0 = ((const float4*)xp)[0];
            float4 v1 = ((const float4*)xp)[1];
            float vv[8] = {v0.x, v0.y, v0.z, v0.w, v1.x, v1.y, v1.z, v1.w};
            f16x8 hv;
            #pragma unroll
            for (int j = 0; j < 8; ++j) hv[j] = (__fp16)vv[j];
            xh[t][mt] = hv;
        }

    // ---------------- depths 0..2: single node per wave, immediate epilogue ----------------
    #pragma unroll
    for (int d = 0; d < 3; ++d) {
        const int nd = 1 << d;
        const int stride = 128 >> d, half = 64 >> d;
        if (wv < nd) {
            const int n = nd - 1 + wv;
            f16x8 w[4];
            loadW(wfrag, n, l, w);
            const float4 b1q = ((const float4*)(b1 + n * 16))[quad];
            const float4 w2q = ((const float4*)(w2 + n * 16))[quad];
            const float4 wpq = ((const float4*)(W1 + (size_t)n * EFF + 128 * 16))[quad];
            const float4 wgq = ((const float4*)(W1 + (size_t)n * EFF + 129 * 16))[quad];
            const float  b2v = b2[n];
            float par[4], gp[4];
            #pragma unroll
            for (int mt = 0; mt < 4; ++mt) {
                const int scol = mt * 16 + col;
                par[mt] = (d >= 1) ? scbuf[(nd >> 1) - 1 + (wv >> 1)][scol] : 0.0f;
                gp[mt]  = (d >= 2) ? scbuf[(nd >> 2) - 1 + (wv >> 2)][scol] : 0.0f;
            }
            const int   slot = wv * stride;
            const float ppar = pp[slot][l];

            f32x4 binit = {b1q.x, b1q.y, b1q.z, b1q.w};
            f32x4 acc[4] = {binit, binit, binit, binit};
            mfma16(w, xh, acc);

            const float sv = epi_score(acc, w2q, wpq, wgq, par, gp, b2v, quad);
            scbuf[nd - 1 + wv][l] = sv;
            const float p = 1.0f / (1.0f + __expf(-sv));
            pp[slot][l]        = ppar * p;
            pp[slot + half][l] = ppar * (1.0f - p);
        }
        if (d < 2) __syncthreads();
    }

    // ---------------- depths 3..6: node-pair iterations, wave-local ----------------
    for (int d = 3; d < 7; ++d) {
        const int nd = 1 << d;
        const int stride = 128 >> d, half = 64 >> d;
        const int base = nd - 1, scPo = (nd >> 1) - 1, scP2o = (nd >> 2) - 1;
        const int ilo = wv * (nd >> 3), ihi = ilo + (nd >> 3);
        for (int i = ilo; i < ihi; ++i) {
            const int nA = base + 2 * i, nB = nA + 1;

            f16x8 wA[4], wB[4];
            loadW(wfrag, nA, l, wA);
            loadW(wfrag, nB, l, wB);
            const float4 b1A = ((const float4*)(b1 + nA * 16))[quad];
            const float4 b1B = ((const float4*)(b1 + nB * 16))[quad];
            const float4 w2A = ((const float4*)(w2 + nA * 16))[quad];
            const float4 w2B = ((const float4*)(w2 + nB * 16))[quad];
            const float4 wpA = ((const float4*)(W1 + (size_t)nA * EFF + 128 * 16))[quad];
            const float4 wpB = ((const float4*)(W1 + (size_t)nB * EFF + 128 * 16))[quad];
            const float4 wgA = ((const float4*)(W1 + (size_t)nA * EFF + 129 * 16))[quad];
            const float4 wgB = ((const float4*)(W1 + (size_t)nB * EFF + 129 * 16))[quad];
            const float  b2A = b2[nA], b2B = b2[nB];
            float par[4], gp[4];                       // shared: same parent/grandparent
            #pragma unroll
            for (int mt = 0; mt < 4; ++mt) {
                const int scol = mt * 16 + col;
                par[mt] = scbuf[scPo + i][scol];
                gp[mt]  = scbuf[scP2o + (i >> 1)][scol];
            }
            const int   slotA = (2 * i) * stride, slotB = slotA + stride;
            const float pparA = pp[slotA][l], pparB = pp[slotB][l];

            f32x4 iAi = {b1A.x, b1A.y, b1A.z, b1A.w};
            f32x4 iBi = {b1B.x, b1B.y, b1B.z, b1B.w};
            f32x4 accA[4] = {iAi, iAi, iAi, iAi};
            f32x4 accB[4] = {iBi, iBi, iBi, iBi};
            mfma16(wA, xh, accA);
            mfma16(wB, xh, accB);

            const float svA = epi_score(accA, w2A, wpA, wgA, par, gp, b2A, quad);
            const float svB = epi_score(accB, w2B, wpB, wgB, par, gp, b2B, quad);
            scbuf[base + 2 * i][l]     = svA;
            scbuf[base + 2 * i + 1][l] = svB;
            const float pA = 1.0f / (1.0f + __expf(-svA));
            const float pB = 1.0f / (1.0f + __expf(-svB));
            pp[slotA][l]        = pparA * pA;
            pp[slotA + half][l] = pparA * (1.0f - pA);
            pp[slotB][l]        = pparB * pB;
            pp[slotB + half][l] = pparB * (1.0f - pB);
        }
    }

    // ---------------- depth 7: paired leaf-mixture fold (wave-local) ----------------
    float oacc[NC];
    #pragma unroll
    for (int c = 0; c < NC; ++c) oacc[c] = 0.0f;
    {
        const int ilo = wv * 16, ihi = ilo + 16;
        for (int i = ilo; i < ihi; ++i) {
            const int nA = 127 + 2 * i, nB = nA + 1;

            f16x8 wA[4], wB[4];
            loadW(wfrag, nA, l, wA);
            loadW(wfrag, nB, l, wB);
            const float4 b1A = ((const float4*)(b1 + nA * 16))[quad];
            const float4 b1B = ((const float4*)(b1 + nB * 16))[quad];
            const float4 w2A = ((const float4*)(w2 + nA * 16))[quad];
            const float4 w2B = ((const float4*)(w2 + nB * 16))[quad];
            const float4 wpA = ((const float4*)(W1 + (size_t)nA * EFF + 128 * 16))[quad];
            const float4 wpB = ((const float4*)(W1 + (size_t)nB * EFF + 128 * 16))[quad];
            const float4 wgA = ((const float4*)(W1 + (size_t)nA * EFF + 129 * 16))[quad];
            const float4 wgB = ((const float4*)(W1 + (size_t)nB * EFF + 129 * 16))[quad];
            const float  b2A = b2[nA], b2B = b2[nB];
            float par[4], gp[4];
            #pragma unroll
            for (int mt = 0; mt < 4; ++mt) {
                const int scol = mt * 16 + col;
                par[mt] = scbuf[63 + i][scol];
                gp[mt]  = scbuf[31 + (i >> 1)][scol];
            }
            const float pparA = pp[2 * i][l], pparB = pp[2 * i + 1][l];

            f32x4 iAi = {b1A.x, b1A.y, b1A.z, b1A.w};
            f32x4 iBi = {b1B.x, b1B.y, b1B.z, b1B.w};
            f32x4 accA[4] = {iAi, iAi, iAi, iAi};
            f32x4 accB[4] = {iBi, iBi, iBi, iBi};
            mfma16(wA, xh, accA);
            mfma16(wB, xh, accB);

            // leaf rows 4i..4i+3 (40 consecutive floats, 16B aligned): 10x dwordx4.
            // Issued here so the latency hides under the two epilogue chains.
            const float4* lp4 = (const float4*)(leaf_logits + (size_t)(4 * i) * NC);
            float4 lv[10];
            #pragma unroll
            for (int q = 0; q < 10; ++q) lv[q] = lp4[q];
            const float* lf = (const float*)lv;

            const float svA = epi_score(accA, w2A, wpA, wgA, par, gp, b2A, quad);
            const float svB = epi_score(accB, w2B, wpB, wgB, par, gp, b2B, quad);
            const float pA = 1.0f / (1.0f + __expf(-svA));
            const float pB = 1.0f / (1.0f + __expf(-svB));
            const float pLA = pparA * pA, pRA = pparA * (1.0f - pA);
            const float pLB = pparB * pB, pRB = pparB * (1.0f - pB);
            #pragma unroll
            for (int c = 0; c < NC; ++c)
                oacc[c] = fmaf(pLA, lf[c], fmaf(pRA, lf[NC + c], oacc[c]));
            #pragma unroll
            for (int c = 0; c < NC; ++c)
                oacc[c] = fmaf(pLB, lf[2 * NC + c], fmaf(pRB, lf[3 * NC + c], oacc[c]));
        }
    }

    // ---------------- cross-wave out reduction through scbuf ----------------
    __syncthreads();
    {
        float* red = &scbuf[0][0];         // 4*64*10 = 2560 floats <= 8128
        #pragma unroll
        for (int c = 0; c < NC; ++c)
            red[(wv * 64 + l) * NC + c] = oacc[c];
    }
    __syncthreads();
    {
        const float* red = &scbuf[0][0];
        for (int i = tid; i < TS * NC; i += BLOCK) {
            float v = red[i] + red[640 + i] + red[1280 + i] + red[1920 + i];
            out[(size_t)s0 * NC + i] = v;
        }
    }
}

} // namespace

extern "C" void kernel_launch(void* const* d_in, const int* in_sizes, int n_in,
                              void* d_out, int out_size, void* d_ws, size_t ws_size,
                              hipStream_t stream) {
    const float* x           = (const float*)d_in[0];
    const float* path_prob   = (const float*)d_in[1];
    const float* W1          = (const float*)d_in[2];
    const float* b1          = (const float*)d_in[3];
    const float* w2          = (const float*)d_in[4];
    const float* b2          = (const float*)d_in[5];
    const float* leaf_logits = (const float*)d_in[6];
    float* out = (float*)d_out;

    const int batch = in_sizes[0] / IN_DIM;                // 32768
    f16x8* wfrag = (f16x8*)d_ws;                           // 255*4*64*16B ~= 1.04 MB

    hipLaunchKernelGGL(prep_w1, dim3(NODES), dim3(256), 0, stream, W1, wfrag);
    hipLaunchKernelGGL(tree_mfma, dim3(batch / TS), dim3(BLOCK), 0, stream,
                       x, path_prob, W1, b1, w2, b2, leaf_logits, wfrag, out);
}

// Round 6
// 135.481 us; speedup vs baseline: 1.1840x; 1.0488x over previous
//
#include <hip/hip_runtime.h>
#include <math.h>

namespace {

typedef __attribute__((ext_vector_type(8))) __fp16 f16x8;
typedef __attribute__((ext_vector_type(4))) float f32x4;

constexpr int IN_DIM = 128;
constexpr int EFF    = 130 * 16;   // W1 node stride (floats)
constexpr int NODES  = 255;
constexpr int TS     = 64;         // samples per block (4 MFMA N-tiles per wave)
constexpr int BLOCK  = 256;
constexpr int NC     = 10;

// ---- prep: W1[:, :128, :] -> MFMA fragment layout, fp16 (single product) ----
// frag element (n, t, lane l, j): W[k = t*32 + (l>>4)*8 + j][hid = l&15]
__global__ __launch_bounds__(256) void prep_w1(const float* __restrict__ W1,
                                               f16x8* __restrict__ wfrag) {
    __shared__ float xs[IN_DIM * 16];      // 8 KB: rows 0..127 of this node
    const int n = blockIdx.x, tid = threadIdx.x;
    const float4* src = (const float4*)(W1 + (size_t)n * EFF);
    ((float4*)xs)[tid]       = src[tid];
    ((float4*)xs)[tid + 256] = src[tid + 256];
    __syncthreads();
    const int l = tid & 63, t = tid >> 6;
    const int k0 = t * 32 + (l >> 4) * 8, hid = l & 15;
    f16x8 hv;
    #pragma unroll
    for (int j = 0; j < 8; ++j)
        hv[j] = (__fp16)xs[(k0 + j) * 16 + hid];   // RNE
    wfrag[(n * 4 + t) * 64 + l] = hv;
}

__device__ __forceinline__ void loadW(const f16x8* __restrict__ wfrag, int n, int l,
                                      f16x8 (&w)[4]) {
    const f16x8* wp = wfrag + (size_t)n * 256 + l;
    #pragma unroll
    for (int t = 0; t < 4; ++t) w[t] = wp[t * 64];
}

__device__ __forceinline__ void mfma16(const f16x8 (&w)[4], const f16x8 (&xh)[4][4],
                                       f32x4 (&acc)[4]) {
    #pragma unroll
    for (int t = 0; t < 4; ++t)
        #pragma unroll
        for (int mt = 0; mt < 4; ++mt)
            acc[mt] = __builtin_amdgcn_mfma_f32_16x16x32_f16(w[t], xh[t][mt], acc[mt], 0, 0, 0);
}

#define COMP4(v, r) ((r == 0) ? v.x : (r == 1) ? v.y : (r == 2) ? v.z : v.w)

// combine + hid-reduce, butterfly reduce-scatter (3 shfl + 3 add + 6 selects).
// Only the association of the 4-lane sum differs from R15 (<=1 ulp).
__device__ __forceinline__ float epi_score(
    const f32x4 (&acc)[4], const float4& w2q, const float4& wpq, const float4& wgq,
    const float (&par)[4], const float (&gp)[4], float b2v, int quad)
{
    float p4[4];
    #pragma unroll
    for (int mt = 0; mt < 4; ++mt) {
        float ts = 0.0f;
        #pragma unroll
        for (int r = 0; r < 4; ++r) {
            const float wpr = COMP4(wpq, r);
            const float wgr = COMP4(wgq, r);
            const float w2r = COMP4(w2q, r);
            const float h = fmaf(par[mt], wpr, fmaf(gp[mt], wgr, acc[mt][r]));
            ts = fmaf(fmaxf(h, 0.0f), w2r, ts);
        }
        p4[mt] = ts;
    }
    const bool hiQ = (quad & 2) != 0;
    const bool loQ = (quad & 1) != 0;
    const float a  = hiQ ? p4[2] : p4[0];
    const float b  = hiQ ? p4[3] : p4[1];
    const float sa = hiQ ? p4[0] : p4[2];
    const float sb = hiQ ? p4[1] : p4[3];
    const float uA = a + __shfl_xor(sa, 32);
    const float uB = b + __shfl_xor(sb, 32);
    const float k  = loQ ? uB : uA;
    const float s  = loQ ? uA : uB;
    return k + __shfl_xor(s, 16) + b2v;
}

// ---- main fused tree kernel ----
// R21: combine the two proven-good ingredients. R15's software pipeline
// (prev epilogue overlapped with current loads+MFMA; removing it cost 4% in
// R20) + R20's node-pairing & butterfly (two independent epilogue chains of
// in-iteration ILP, -18% VALU ops, half the iterations, shared par/gp).
// R16-R18 proved residency is pinned at ~2 blocks/CU for every shape ->
// at 2 waves/SIMD the VGPR budget is effectively 256, so the pair-pipeline's
// carried state (2 accs + epilogue scalars, ~70 VGPR) is free until spill.
// Pipeline flows across depth boundaries d3..d6 and through d7 (wave-local
// in-order LDS; validated by R18 phase B). d7 leaf rows load at the top of
// the overlapped epilogue, hidden under the two score chains.
// Ownership identical to R15 -> 2 barriers (after d0, d1); d>=2 wave-local.
__global__ __launch_bounds__(BLOCK) __attribute__((amdgpu_waves_per_eu(2)))
void tree_mfma(
    const float* __restrict__ x, const float* __restrict__ path_prob,
    const float* __restrict__ W1, const float* __restrict__ b1,
    const float* __restrict__ w2, const float* __restrict__ b2,
    const float* __restrict__ leaf_logits,
    const f16x8* __restrict__ wfrag,
    float* __restrict__ out)
{
    __shared__ float pp[128][TS];          // 32 KB: path probs, depths 0..6 only
    __shared__ float scbuf[127][TS];       // 31.75 KB: depth-d scores at row (2^d - 1)

    const int tid  = threadIdx.x;
    const int wv   = tid >> 6, l = tid & 63;
    const int quad = l >> 4,   col = l & 15;
    const int s0   = blockIdx.x * TS;

    if (tid < TS) pp[0][tid] = path_prob[s0 + tid];

    // x fragments (fp16): B operand B[k = t*32+quad*8+j][col]
    f16x8 xh[4][4];
    #pragma unroll
    for (int t = 0; t < 4; ++t)
        #pragma unroll
        for (int mt = 0; mt < 4; ++mt) {
            const float* xp = x + (size_t)(s0 + mt * 16 + col) * IN_DIM + t * 32 + quad * 8;
            float4 v0 = ((const float4*)xp)[0];
            float4 v1 = ((const float4*)xp)[1];
            float vv[8] = {v0.x, v0.y, v0.z, v0.w, v1.x, v1.y, v1.z, v1.w};
            f16x8 hv;
            #pragma unroll
            for (int j = 0; j < 8; ++j) hv[j] = (__fp16)vv[j];
            xh[t][mt] = hv;
        }

    // ---------------- depths 0..2: single node per wave, immediate epilogue ----------------
    #pragma unroll
    for (int d = 0; d < 3; ++d) {
        const int nd = 1 << d;
        const int stride = 128 >> d, half = 64 >> d;
        if (wv < nd) {
            const int n = nd - 1 + wv;
            f16x8 w[4];
            loadW(wfrag, n, l, w);
            const float4 b1q = ((const float4*)(b1 + n * 16))[quad];
            const float4 w2q = ((const float4*)(w2 + n * 16))[quad];
            const float4 wpq = ((const float4*)(W1 + (size_t)n * EFF + 128 * 16))[quad];
            const float4 wgq = ((const float4*)(W1 + (size_t)n * EFF + 129 * 16))[quad];
            const float  b2v = b2[n];
            float par[4], gp[4];
            #pragma unroll
            for (int mt = 0; mt < 4; ++mt) {
                const int scol = mt * 16 + col;
                par[mt] = (d >= 1) ? scbuf[(nd >> 1) - 1 + (wv >> 1)][scol] : 0.0f;
                gp[mt]  = (d >= 2) ? scbuf[(nd >> 2) - 1 + (wv >> 2)][scol] : 0.0f;
            }
            const int   slot = wv * stride;
            const float ppar = pp[slot][l];

            f32x4 binit = {b1q.x, b1q.y, b1q.z, b1q.w};
            f32x4 acc[4] = {binit, binit, binit, binit};
            mfma16(w, xh, acc);

            const float sv = epi_score(acc, w2q, wpq, wgq, par, gp, b2v, quad);
            scbuf[nd - 1 + wv][l] = sv;
            const float p = 1.0f / (1.0f + __expf(-sv));
            pp[slot][l]        = ppar * p;
            pp[slot + half][l] = ppar * (1.0f - p);
        }
        if (d < 2) __syncthreads();
    }

    // ---------------- depths 3..6: pipelined node-pair iterations, wave-local ----------------
    // carried state of the previous pair
    bool   havePrev = false;
    f32x4  cAccA[4], cAccB[4];
    float4 cW2A, cW2B, cWpA, cWpB, cWgA, cWgB;
    float  cB2A = 0.f, cB2B = 0.f, cPparA = 0.f, cPparB = 0.f;
    float  cPar[4], cGp[4];
    int    cScw = 0, cSlotA = 0, cSlotB = 0, cHalf = 0;

    for (int d = 3; d < 7; ++d) {
        const int nd = 1 << d;
        const int stride = 128 >> d, half = 64 >> d;
        const int base = nd - 1, scPo = (nd >> 1) - 1, scP2o = (nd >> 2) - 1;
        const int ilo = wv * (nd >> 3), ihi = ilo + (nd >> 3);
        for (int i = ilo; i < ihi; ++i) {
            const int nA = base + 2 * i, nB = nA + 1;

            // (1) this pair's W + b1 (latency hidden under prev epilogue)
            f16x8 wA[4], wB[4];
            loadW(wfrag, nA, l, wA);
            loadW(wfrag, nB, l, wB);
            const float4 b1A = ((const float4*)(b1 + nA * 16))[quad];
            const float4 b1B = ((const float4*)(b1 + nB * 16))[quad];

            // (2) overlapped epilogue of previous pair (two independent chains)
            if (havePrev) {
                const float svA = epi_score(cAccA, cW2A, cWpA, cWgA, cPar, cGp, cB2A, quad);
                const float svB = epi_score(cAccB, cW2B, cWpB, cWgB, cPar, cGp, cB2B, quad);
                scbuf[cScw][l]     = svA;
                scbuf[cScw + 1][l] = svB;
                const float pA = 1.0f / (1.0f + __expf(-svA));
                const float pB = 1.0f / (1.0f + __expf(-svB));
                pp[cSlotA][l]         = cPparA * pA;
                pp[cSlotA + cHalf][l] = cPparA * (1.0f - pA);
                pp[cSlotB][l]         = cPparB * pB;
                pp[cSlotB + cHalf][l] = cPparB * (1.0f - pB);
            }

            // (3) this pair's epilogue scalars (consumed NEXT iteration)
            const float4 w2A = ((const float4*)(w2 + nA * 16))[quad];
            const float4 w2B = ((const float4*)(w2 + nB * 16))[quad];
            const float4 wpA = ((const float4*)(W1 + (size_t)nA * EFF + 128 * 16))[quad];
            const float4 wpB = ((const float4*)(W1 + (size_t)nB * EFF + 128 * 16))[quad];
            const float4 wgA = ((const float4*)(W1 + (size_t)nA * EFF + 129 * 16))[quad];
            const float4 wgB = ((const float4*)(W1 + (size_t)nB * EFF + 129 * 16))[quad];
            const float  b2A = b2[nA], b2B = b2[nB];
            float par[4], gp[4];                       // shared by the pair
            #pragma unroll
            for (int mt = 0; mt < 4; ++mt) {
                const int scol = mt * 16 + col;
                par[mt] = scbuf[scPo + i][scol];
                gp[mt]  = scbuf[scP2o + (i >> 1)][scol];
            }
            const int   slotA = (2 * i) * stride, slotB = slotA + stride;
            const float pparA = pp[slotA][l], pparB = pp[slotB][l];

            // (4) MFMA pair into fresh accumulators (bias folded into init)
            f32x4 iAi = {b1A.x, b1A.y, b1A.z, b1A.w};
            f32x4 iBi = {b1B.x, b1B.y, b1B.z, b1B.w};
            f32x4 accA[4] = {iAi, iAi, iAi, iAi};
            f32x4 accB[4] = {iBi, iBi, iBi, iBi};
            mfma16(wA, xh, accA);
            mfma16(wB, xh, accB);

            // (5) carry
            #pragma unroll
            for (int mt = 0; mt < 4; ++mt) { cAccA[mt] = accA[mt]; cAccB[mt] = accB[mt]; }
            cW2A = w2A; cW2B = w2B; cWpA = wpA; cWpB = wpB; cWgA = wgA; cWgB = wgB;
            cB2A = b2A; cB2B = b2B; cPparA = pparA; cPparB = pparB;
            #pragma unroll
            for (int mt = 0; mt < 4; ++mt) { cPar[mt] = par[mt]; cGp[mt] = gp[mt]; }
            cScw = base + 2 * i; cSlotA = slotA; cSlotB = slotB; cHalf = half;
            havePrev = true;
        }
    }
    // drain last d=6 pair
    if (havePrev) {
        const float svA = epi_score(cAccA, cW2A, cWpA, cWgA, cPar, cGp, cB2A, quad);
        const float svB = epi_score(cAccB, cW2B, cWpB, cWgB, cPar, cGp, cB2B, quad);
        scbuf[cScw][l]     = svA;
        scbuf[cScw + 1][l] = svB;
        const float pA = 1.0f / (1.0f + __expf(-svA));
        const float pB = 1.0f / (1.0f + __expf(-svB));
        pp[cSlotA][l]         = cPparA * pA;
        pp[cSlotA + cHalf][l] = cPparA * (1.0f - pA);
        pp[cSlotB][l]         = cPparB * pB;
        pp[cSlotB + cHalf][l] = cPparB * (1.0f - pB);
    }

    // ---------------- depth 7: pipelined paired leaf-mixture fold (wave-local) ----------------
    float oacc[NC];
    #pragma unroll
    for (int c = 0; c < NC; ++c) oacc[c] = 0.0f;
    {
        bool hp = false;
        int  cPl = 0;
        const int ilo = wv * 16, ihi = ilo + 16;
        for (int i = ilo; i < ihi; ++i) {
            const int nA = 127 + 2 * i, nB = nA + 1;

            // (1) this pair's W + b1
            f16x8 wA[4], wB[4];
            loadW(wfrag, nA, l, wA);
            loadW(wfrag, nB, l, wB);
            const float4 b1A = ((const float4*)(b1 + nA * 16))[quad];
            const float4 b1B = ((const float4*)(b1 + nB * 16))[quad];

            // (2) overlapped epilogue of previous pair; leaf rows issued first
            //     so their latency hides under the two score chains
            if (hp) {
                const float4* lp4 = (const float4*)(leaf_logits + (size_t)(4 * cPl) * NC);
                float4 lv[10];
                #pragma unroll
                for (int q = 0; q < 10; ++q) lv[q] = lp4[q];
                const float* lf = (const float*)lv;

                const float svA = epi_score(cAccA, cW2A, cWpA, cWgA, cPar, cGp, cB2A, quad);
                const float svB = epi_score(cAccB, cW2B, cWpB, cWgB, cPar, cGp, cB2B, quad);
                const float pA = 1.0f / (1.0f + __expf(-svA));
                const float pB = 1.0f / (1.0f + __expf(-svB));
                const float pLA = cPparA * pA, pRA = cPparA * (1.0f - pA);
                const float pLB = cPparB * pB, pRB = cPparB * (1.0f - pB);
                #pragma unroll
                for (int c = 0; c < NC; ++c)
                    oacc[c] = fmaf(pLA, lf[c], fmaf(pRA, lf[NC + c], oacc[c]));
                #pragma unroll
                for (int c = 0; c < NC; ++c)
                    oacc[c] = fmaf(pLB, lf[2 * NC + c], fmaf(pRB, lf[3 * NC + c], oacc[c]));
            }

            // (3) this pair's epilogue scalars
            const float4 w2A = ((const float4*)(w2 + nA * 16))[quad];
            const float4 w2B = ((const float4*)(w2 + nB * 16))[quad];
            const float4 wpA = ((const float4*)(W1 + (size_t)nA * EFF + 128 * 16))[quad];
            const float4 wpB = ((const float4*)(W1 + (size_t)nB * EFF + 128 * 16))[quad];
            const float4 wgA = ((const float4*)(W1 + (size_t)nA * EFF + 129 * 16))[quad];
            const float4 wgB = ((const float4*)(W1 + (size_t)nB * EFF + 129 * 16))[quad];
            const float  b2A = b2[nA], b2B = b2[nB];
            float par[4], gp[4];
            #pragma unroll
            for (int mt = 0; mt < 4; ++mt) {
                const int scol = mt * 16 + col;
                par[mt] = scbuf[63 + i][scol];
                gp[mt]  = scbuf[31 + (i >> 1)][scol];
            }
            const float pparA = pp[2 * i][l], pparB = pp[2 * i + 1][l];

            // (4) MFMA
            f32x4 iAi = {b1A.x, b1A.y, b1A.z, b1A.w};
            f32x4 iBi = {b1B.x, b1B.y, b1B.z, b1B.w};
            f32x4 accA[4] = {iAi, iAi, iAi, iAi};
            f32x4 accB[4] = {iBi, iBi, iBi, iBi};
            mfma16(wA, xh, accA);
            mfma16(wB, xh, accB);

            // (5) carry
            #pragma unroll
            for (int mt = 0; mt < 4; ++mt) { cAccA[mt] = accA[mt]; cAccB[mt] = accB[mt]; }
            cW2A = w2A; cW2B = w2B; cWpA = wpA; cWpB = wpB; cWgA = wgA; cWgB = wgB;
            cB2A = b2A; cB2B = b2B; cPparA = pparA; cPparB = pparB;
            #pragma unroll
            for (int mt = 0; mt < 4; ++mt) { cPar[mt] = par[mt]; cGp[mt] = gp[mt]; }
            cPl = i;
            hp = true;
        }
        // drain last leaf pair
        if (hp) {
            const float4* lp4 = (const float4*)(leaf_logits + (size_t)(4 * cPl) * NC);
            float4 lv[10];
            #pragma unroll
            for (int q = 0; q < 10; ++q) lv[q] = lp4[q];
            const float* lf = (const float*)lv;

            const float svA = epi_score(cAccA, cW2A, cWpA, cWgA, cPar, cGp, cB2A, quad);
            const float svB = epi_score(cAccB, cW2B, cWpB, cWgB, cPar, cGp, cB2B, quad);
            const float pA = 1.0f / (1.0f + __expf(-svA));
            const float pB = 1.0f / (1.0f + __expf(-svB));
            const float pLA = cPparA * pA, pRA = cPparA * (1.0f - pA);
            const float pLB = cPparB * pB, pRB = cPparB * (1.0f - pB);
            #pragma unroll
            for (int c = 0; c < NC; ++c)
                oacc[c] = fmaf(pLA, lf[c], fmaf(pRA, lf[NC + c], oacc[c]));
            #pragma unroll
            for (int c = 0; c < NC; ++c)
                oacc[c] = fmaf(pLB, lf[2 * NC + c], fmaf(pRB, lf[3 * NC + c], oacc[c]));
        }
    }

    // ---------------- cross-wave out reduction through scbuf ----------------
    __syncthreads();
    {
        float* red = &scbuf[0][0];         // 4*64*10 = 2560 floats <= 8128
        #pragma unroll
        for (int c = 0; c < NC; ++c)
            red[(wv * 64 + l) * NC + c] = oacc[c];
    }
    __syncthreads();
    {
        const float* red = &scbuf[0][0];
        for (int i = tid; i < TS * NC; i += BLOCK) {
            float v = red[i] + red[640 + i] + red[1280 + i] + red[1920 + i];
            out[(size_t)s0 * NC + i] = v;
        }
    }
}

} // namespace

extern "C" void kernel_launch(void* const* d_in, const int* in_sizes, int n_in,
                              void* d_out, int out_size, void* d_ws, size_t ws_size,
                              hipStream_t stream) {
    const float* x           = (const float*)d_in[0];
    const float* path_prob   = (const float*)d_in[1];
    const float* W1          = (const float*)d_in[2];
    const float* b1          = (const float*)d_in[3];
    const float* w2          = (const float*)d_in[4];
    const float* b2          = (const float*)d_in[5];
    const float* leaf_logits = (const float*)d_in[6];
    float* out = (float*)d_out;

    const int batch = in_sizes[0] / IN_DIM;                // 32768
    f16x8* wfrag = (f16x8*)d_ws;                           // 255*4*64*16B ~= 1.04 MB

    hipLaunchKernelGGL(prep_w1, dim3(NODES), dim3(256), 0, stream, W1, wfrag);
    hipLaunchKernelGGL(tree_mfma, dim3(batch / TS), dim3(BLOCK), 0, stream,
                       x, path_prob, W1, b1, w2, b2, leaf_logits, wfrag, out);
}

// Round 7
// 128.279 us; speedup vs baseline: 1.2505x; 1.0561x over previous
//
#include <hip/hip_runtime.h>
#include <math.h>

namespace {

typedef __attribute__((ext_vector_type(8))) __fp16 f16x8;
typedef __attribute__((ext_vector_type(4))) float f32x4;

constexpr int IN_DIM = 128;
constexpr int EFF    = 130 * 16;   // W1 node stride (floats)
constexpr int NODES  = 255;
constexpr int TS     = 64;         // samples per block (4 MFMA N-tiles per wave)
constexpr int BLOCK  = 256;
constexpr int NC     = 10;

// ---- prep: W1[:, :128, :] -> MFMA fragment layout, fp16 (single product) ----
// frag element (n, t, lane l, j): W[k = t*32 + (l>>4)*8 + j][hid = l&15]
__global__ __launch_bounds__(256) void prep_w1(const float* __restrict__ W1,
                                               f16x8* __restrict__ wfrag) {
    __shared__ float xs[IN_DIM * 16];      // 8 KB: rows 0..127 of this node
    const int n = blockIdx.x, tid = threadIdx.x;
    const float4* src = (const float4*)(W1 + (size_t)n * EFF);
    ((float4*)xs)[tid]       = src[tid];
    ((float4*)xs)[tid + 256] = src[tid + 256];
    __syncthreads();
    const int l = tid & 63, t = tid >> 6;
    const int k0 = t * 32 + (l >> 4) * 8, hid = l & 15;
    f16x8 hv;
    #pragma unroll
    for (int j = 0; j < 8; ++j)
        hv[j] = (__fp16)xs[(k0 + j) * 16 + hid];   // RNE
    wfrag[(n * 4 + t) * 64 + l] = hv;
}

__device__ __forceinline__ void loadW(const f16x8* __restrict__ wfrag, int n, int l,
                                      f16x8 (&w)[4]) {
    const f16x8* wp = wfrag + (size_t)n * 256 + l;
    #pragma unroll
    for (int t = 0; t < 4; ++t) w[t] = wp[t * 64];
}

__device__ __forceinline__ void mfma16(const f16x8 (&w)[4], const f16x8 (&xh)[4][4],
                                       f32x4 (&acc)[4]) {
    #pragma unroll
    for (int t = 0; t < 4; ++t)
        #pragma unroll
        for (int mt = 0; mt < 4; ++mt)
            acc[mt] = __builtin_amdgcn_mfma_f32_16x16x32_f16(w[t], xh[t][mt], acc[mt], 0, 0, 0);
}

#define COMP4(v, r) ((r == 0) ? v.x : (r == 1) ? v.y : (r == 2) ? v.z : v.w)

// combine + hid-reduce, butterfly reduce-scatter (3 shfl + 3 add + 6 selects).
__device__ __forceinline__ float epi_score(
    const f32x4 (&acc)[4], const float4& w2q, const float4& wpq, const float4& wgq,
    const float (&par)[4], const float (&gp)[4], float b2v, int quad)
{
    float p4[4];
    #pragma unroll
    for (int mt = 0; mt < 4; ++mt) {
        float ts = 0.0f;
        #pragma unroll
        for (int r = 0; r < 4; ++r) {
            const float wpr = COMP4(wpq, r);
            const float wgr = COMP4(wgq, r);
            const float w2r = COMP4(w2q, r);
            const float h = fmaf(par[mt], wpr, fmaf(gp[mt], wgr, acc[mt][r]));
            ts = fmaf(fmaxf(h, 0.0f), w2r, ts);
        }
        p4[mt] = ts;
    }
    const bool hiQ = (quad & 2) != 0;
    const bool loQ = (quad & 1) != 0;
    const float a  = hiQ ? p4[2] : p4[0];
    const float b  = hiQ ? p4[3] : p4[1];
    const float sa = hiQ ? p4[0] : p4[2];
    const float sb = hiQ ? p4[1] : p4[3];
    const float uA = a + __shfl_xor(sa, 32);
    const float uB = b + __shfl_xor(sb, 32);
    const float k  = loQ ? uB : uA;
    const float s  = loQ ? uA : uB;
    return k + __shfl_xor(s, 16) + b2v;
}

// ---- main fused tree kernel ----
// R22 = R21 body + three changes:
// (a) Barrier-free redundant head: every wave computes its own ancestor chain
//     node0 -> node(1+(wv>>1)) -> node(3+wv) with scores/pp in REGISTERS and
//     par/gp via __shfl of its own registers. All cross-wave deps vanish ->
//     ZERO barriers until the output reduction (was 2 + drains). Redundant
//     values are bitwise identical across waves (same xh, same loads), so the
//     two double-written scbuf rows (1,2) are benign same-value writes.
//     Head writes for the body: scbuf[1+(wv>>1)]=sc1, scbuf[3+wv]=sc2,
//     pp[32wv]=ppL2, pp[32wv+16]=ppR2 (sole writer each; self-read at d3/d4).
// (b) s_setprio(1) around each paired MFMA burst: with no barriers the 2
//     waves/SIMD drift into {epilogue-VALU} vs {MFMA} roles -> arbitration
//     pays (T5 regime). Rollback if regression.
// (c) readfirstlane(wv): node indices become SGPR-known -> scalar addressing.
// Arithmetic bitwise identical to R21 -> absmax must stay 0.001953125.
__global__ __launch_bounds__(BLOCK) __attribute__((amdgpu_waves_per_eu(2)))
void tree_mfma(
    const float* __restrict__ x, const float* __restrict__ path_prob,
    const float* __restrict__ W1, const float* __restrict__ b1,
    const float* __restrict__ w2, const float* __restrict__ b2,
    const float* __restrict__ leaf_logits,
    const f16x8* __restrict__ wfrag,
    float* __restrict__ out)
{
    __shared__ float pp[128][TS];          // 32 KB: path probs, depths 3..7
    __shared__ float scbuf[127][TS];       // 31.75 KB: depth-d scores at row (2^d - 1)

    const int tid  = threadIdx.x;
    const int wv   = __builtin_amdgcn_readfirstlane(tid >> 6);
    const int l    = tid & 63;
    const int quad = l >> 4,   col = l & 15;
    const int s0   = blockIdx.x * TS;

    // x fragments (fp16): B operand B[k = t*32+quad*8+j][col]
    f16x8 xh[4][4];
    #pragma unroll
    for (int t = 0; t < 4; ++t)
        #pragma unroll
        for (int mt = 0; mt < 4; ++mt) {
            const float* xp = x + (size_t)(s0 + mt * 16 + col) * IN_DIM + t * 32 + quad * 8;
            float4 v0 = ((const float4*)xp)[0];
            float4 v1 = ((const float4*)xp)[1];
            float vv[8] = {v0.x, v0.y, v0.z, v0.w, v1.x, v1.y, v1.z, v1.w};
            f16x8 hv;
            #pragma unroll
            for (int j = 0; j < 8; ++j) hv[j] = (__fp16)vv[j];
            xh[t][mt] = hv;
        }

    // ---------------- barrier-free redundant head: d0 -> d1 -> d2 ----------------
    const int j1 = wv >> 1;                // this wave's d1 ancestor
    float sc0, sc1, sc2;
    const float z4[4] = {0.0f, 0.0f, 0.0f, 0.0f};

    {   // d0: node 0 (all waves, redundant)
        f16x8 w[4];
        loadW(wfrag, 0, l, w);
        const float4 b1q = ((const float4*)(b1))[quad];
        const float4 w2q = ((const float4*)(w2))[quad];
        const float4 wpq = ((const float4*)(W1 + 128 * 16))[quad];
        const float4 wgq = ((const float4*)(W1 + 129 * 16))[quad];
        const float  b2v = b2[0];
        f32x4 binit = {b1q.x, b1q.y, b1q.z, b1q.w};
        f32x4 acc[4] = {binit, binit, binit, binit};
        __builtin_amdgcn_s_setprio(1);
        mfma16(w, xh, acc);
        __builtin_amdgcn_s_setprio(0);
        sc0 = epi_score(acc, w2q, wpq, wgq, z4, z4, b2v, quad);
    }
    const float pp0 = path_prob[s0 + l];
    const float p0  = 1.0f / (1.0f + __expf(-sc0));
    const float pp1 = (j1 == 0) ? pp0 * p0 : pp0 * (1.0f - p0);

    float pp2;
    {   // d1: node 1 + j1 (this wave's ancestor)
        const int n = 1 + j1;
        f16x8 w[4];
        loadW(wfrag, n, l, w);
        const float4 b1q = ((const float4*)(b1 + n * 16))[quad];
        const float4 w2q = ((const float4*)(w2 + n * 16))[quad];
        const float4 wpq = ((const float4*)(W1 + (size_t)n * EFF + 128 * 16))[quad];
        const float4 wgq = ((const float4*)(W1 + (size_t)n * EFF + 129 * 16))[quad];
        const float  b2v = b2[n];
        float par[4];
        #pragma unroll
        for (int mt = 0; mt < 4; ++mt) par[mt] = __shfl(sc0, mt * 16 + col);
        f32x4 binit = {b1q.x, b1q.y, b1q.z, b1q.w};
        f32x4 acc[4] = {binit, binit, binit, binit};
        __builtin_amdgcn_s_setprio(1);
        mfma16(w, xh, acc);
        __builtin_amdgcn_s_setprio(0);
        sc1 = epi_score(acc, w2q, wpq, wgq, par, z4, b2v, quad);
        const float p = 1.0f / (1.0f + __expf(-sc1));
        pp2 = ((wv & 1) == 0) ? pp1 * p : pp1 * (1.0f - p);
    }

    {   // d2: node 3 + wv (own subtree root)
        const int n = 3 + wv;
        f16x8 w[4];
        loadW(wfrag, n, l, w);
        const float4 b1q = ((const float4*)(b1 + n * 16))[quad];
        const float4 w2q = ((const float4*)(w2 + n * 16))[quad];
        const float4 wpq = ((const float4*)(W1 + (size_t)n * EFF + 128 * 16))[quad];
        const float4 wgq = ((const float4*)(W1 + (size_t)n * EFF + 129 * 16))[quad];
        const float  b2v = b2[n];
        float par[4], gp[4];
        #pragma unroll
        for (int mt = 0; mt < 4; ++mt) {
            const int scol = mt * 16 + col;
            par[mt] = __shfl(sc1, scol);
            gp[mt]  = __shfl(sc0, scol);
        }
        f32x4 binit = {b1q.x, b1q.y, b1q.z, b1q.w};
        f32x4 acc[4] = {binit, binit, binit, binit};
        __builtin_amdgcn_s_setprio(1);
        mfma16(w, xh, acc);
        __builtin_amdgcn_s_setprio(0);
        sc2 = epi_score(acc, w2q, wpq, wgq, par, gp, b2v, quad);
        const float p = 1.0f / (1.0f + __expf(-sc2));
        // hand off to the d3+ body (sole writer per location; self-read later)
        pp[32 * wv][l]      = pp2 * p;
        pp[32 * wv + 16][l] = pp2 * (1.0f - p);
        scbuf[1 + j1][l] = sc1;            // d3 gp (benign double write, identical bits)
        scbuf[3 + wv][l] = sc2;            // d3 par + d4 gp
    }

    // ---------------- depths 3..6: pipelined node-pair iterations, wave-local ----------------
    bool   havePrev = false;
    f32x4  cAccA[4], cAccB[4];
    float4 cW2A, cW2B, cWpA, cWpB, cWgA, cWgB;
    float  cB2A = 0.f, cB2B = 0.f, cPparA = 0.f, cPparB = 0.f;
    float  cPar[4], cGp[4];
    int    cScw = 0, cSlotA = 0, cSlotB = 0, cHalf = 0;

    for (int d = 3; d < 7; ++d) {
        const int nd = 1 << d;
        const int stride = 128 >> d, half = 64 >> d;
        const int base = nd - 1, scPo = (nd >> 1) - 1, scP2o = (nd >> 2) - 1;
        const int ilo = wv * (nd >> 3), ihi = ilo + (nd >> 3);
        for (int i = ilo; i < ihi; ++i) {
            const int nA = base + 2 * i, nB = nA + 1;

            // (1) this pair's W + b1 (latency hidden under prev epilogue)
            f16x8 wA[4], wB[4];
            loadW(wfrag, nA, l, wA);
            loadW(wfrag, nB, l, wB);
            const float4 b1A = ((const float4*)(b1 + nA * 16))[quad];
            const float4 b1B = ((const float4*)(b1 + nB * 16))[quad];

            // (2) overlapped epilogue of previous pair (two independent chains)
            if (havePrev) {
                const float svA = epi_score(cAccA, cW2A, cWpA, cWgA, cPar, cGp, cB2A, quad);
                const float svB = epi_score(cAccB, cW2B, cWpB, cWgB, cPar, cGp, cB2B, quad);
                scbuf[cScw][l]     = svA;
                scbuf[cScw + 1][l] = svB;
                const float pA = 1.0f / (1.0f + __expf(-svA));
                const float pB = 1.0f / (1.0f + __expf(-svB));
                pp[cSlotA][l]         = cPparA * pA;
                pp[cSlotA + cHalf][l] = cPparA * (1.0f - pA);
                pp[cSlotB][l]         = cPparB * pB;
                pp[cSlotB + cHalf][l] = cPparB * (1.0f - pB);
            }

            // (3) this pair's epilogue scalars (consumed NEXT iteration)
            const float4 w2A = ((const float4*)(w2 + nA * 16))[quad];
            const float4 w2B = ((const float4*)(w2 + nB * 16))[quad];
            const float4 wpA = ((const float4*)(W1 + (size_t)nA * EFF + 128 * 16))[quad];
            const float4 wpB = ((const float4*)(W1 + (size_t)nB * EFF + 128 * 16))[quad];
            const float4 wgA = ((const float4*)(W1 + (size_t)nA * EFF + 129 * 16))[quad];
            const float4 wgB = ((const float4*)(W1 + (size_t)nB * EFF + 129 * 16))[quad];
            const float  b2A = b2[nA], b2B = b2[nB];
            float par[4], gp[4];                       // shared by the pair
            #pragma unroll
            for (int mt = 0; mt < 4; ++mt) {
                const int scol = mt * 16 + col;
                par[mt] = scbuf[scPo + i][scol];
                gp[mt]  = scbuf[scP2o + (i >> 1)][scol];
            }
            const int   slotA = (2 * i) * stride, slotB = slotA + stride;
            const float pparA = pp[slotA][l], pparB = pp[slotB][l];

            // (4) MFMA pair into fresh accumulators (bias folded into init)
            f32x4 iAi = {b1A.x, b1A.y, b1A.z, b1A.w};
            f32x4 iBi = {b1B.x, b1B.y, b1B.z, b1B.w};
            f32x4 accA[4] = {iAi, iAi, iAi, iAi};
            f32x4 accB[4] = {iBi, iBi, iBi, iBi};
            __builtin_amdgcn_s_setprio(1);
            mfma16(wA, xh, accA);
            mfma16(wB, xh, accB);
            __builtin_amdgcn_s_setprio(0);

            // (5) carry
            #pragma unroll
            for (int mt = 0; mt < 4; ++mt) { cAccA[mt] = accA[mt]; cAccB[mt] = accB[mt]; }
            cW2A = w2A; cW2B = w2B; cWpA = wpA; cWpB = wpB; cWgA = wgA; cWgB = wgB;
            cB2A = b2A; cB2B = b2B; cPparA = pparA; cPparB = pparB;
            #pragma unroll
            for (int mt = 0; mt < 4; ++mt) { cPar[mt] = par[mt]; cGp[mt] = gp[mt]; }
            cScw = base + 2 * i; cSlotA = slotA; cSlotB = slotB; cHalf = half;
            havePrev = true;
        }
    }
    // drain last d=6 pair
    if (havePrev) {
        const float svA = epi_score(cAccA, cW2A, cWpA, cWgA, cPar, cGp, cB2A, quad);
        const float svB = epi_score(cAccB, cW2B, cWpB, cWgB, cPar, cGp, cB2B, quad);
        scbuf[cScw][l]     = svA;
        scbuf[cScw + 1][l] = svB;
        const float pA = 1.0f / (1.0f + __expf(-svA));
        const float pB = 1.0f / (1.0f + __expf(-svB));
        pp[cSlotA][l]         = cPparA * pA;
        pp[cSlotA + cHalf][l] = cPparA * (1.0f - pA);
        pp[cSlotB][l]         = cPparB * pB;
        pp[cSlotB + cHalf][l] = cPparB * (1.0f - pB);
    }

    // ---------------- depth 7: pipelined paired leaf-mixture fold (wave-local) ----------------
    float oacc[NC];
    #pragma unroll
    for (int c = 0; c < NC; ++c) oacc[c] = 0.0f;
    {
        bool hp = false;
        int  cPl = 0;
        const int ilo = wv * 16, ihi = ilo + 16;
        for (int i = ilo; i < ihi; ++i) {
            const int nA = 127 + 2 * i, nB = nA + 1;

            // (1) this pair's W + b1
            f16x8 wA[4], wB[4];
            loadW(wfrag, nA, l, wA);
            loadW(wfrag, nB, l, wB);
            const float4 b1A = ((const float4*)(b1 + nA * 16))[quad];
            const float4 b1B = ((const float4*)(b1 + nB * 16))[quad];

            // (2) overlapped epilogue of previous pair; leaf rows issued first
            if (hp) {
                const float4* lp4 = (const float4*)(leaf_logits + (size_t)(4 * cPl) * NC);
                float4 lv[10];
                #pragma unroll
                for (int q = 0; q < 10; ++q) lv[q] = lp4[q];
                const float* lf = (const float*)lv;

                const float svA = epi_score(cAccA, cW2A, cWpA, cWgA, cPar, cGp, cB2A, quad);
                const float svB = epi_score(cAccB, cW2B, cWpB, cWgB, cPar, cGp, cB2B, quad);
                const float pA = 1.0f / (1.0f + __expf(-svA));
                const float pB = 1.0f / (1.0f + __expf(-svB));
                const float pLA = cPparA * pA, pRA = cPparA * (1.0f - pA);
                const float pLB = cPparB * pB, pRB = cPparB * (1.0f - pB);
                #pragma unroll
                for (int c = 0; c < NC; ++c)
                    oacc[c] = fmaf(pLA, lf[c], fmaf(pRA, lf[NC + c], oacc[c]));
                #pragma unroll
                for (int c = 0; c < NC; ++c)
                    oacc[c] = fmaf(pLB, lf[2 * NC + c], fmaf(pRB, lf[3 * NC + c], oacc[c]));
            }

            // (3) this pair's epilogue scalars
            const float4 w2A = ((const float4*)(w2 + nA * 16))[quad];
            const float4 w2B = ((const float4*)(w2 + nB * 16))[quad];
            const float4 wpA = ((const float4*)(W1 + (size_t)nA * EFF + 128 * 16))[quad];
            const float4 wpB = ((const float4*)(W1 + (size_t)nB * EFF + 128 * 16))[quad];
            const float4 wgA = ((const float4*)(W1 + (size_t)nA * EFF + 129 * 16))[quad];
            const float4 wgB = ((const float4*)(W1 + (size_t)nB * EFF + 129 * 16))[quad];
            const float  b2A = b2[nA], b2B = b2[nB];
            float par[4], gp[4];
            #pragma unroll
            for (int mt = 0; mt < 4; ++mt) {
                const int scol = mt * 16 + col;
                par[mt] = scbuf[63 + i][scol];
                gp[mt]  = scbuf[31 + (i >> 1)][scol];
            }
            const float pparA = pp[2 * i][l], pparB = pp[2 * i + 1][l];

            // (4) MFMA
            f32x4 iAi = {b1A.x, b1A.y, b1A.z, b1A.w};
            f32x4 iBi = {b1B.x, b1B.y, b1B.z, b1B.w};
            f32x4 accA[4] = {iAi, iAi, iAi, iAi};
            f32x4 accB[4] = {iBi, iBi, iBi, iBi};
            __builtin_amdgcn_s_setprio(1);
            mfma16(wA, xh, accA);
            mfma16(wB, xh, accB);
            __builtin_amdgcn_s_setprio(0);

            // (5) carry
            #pragma unroll
            for (int mt = 0; mt < 4; ++mt) { cAccA[mt] = accA[mt]; cAccB[mt] = accB[mt]; }
            cW2A = w2A; cW2B = w2B; cWpA = wpA; cWpB = wpB; cWgA = wgA; cWgB = wgB;
            cB2A = b2A; cB2B = b2B; cPparA = pparA; cPparB = pparB;
            #pragma unroll
            for (int mt = 0; mt < 4; ++mt) { cPar[mt] = par[mt]; cGp[mt] = gp[mt]; }
            cPl = i;
            hp = true;
        }
        // drain last leaf pair
        if (hp) {
            const float4* lp4 = (const float4*)(leaf_logits + (size_t)(4 * cPl) * NC);
            float4 lv[10];
            #pragma unroll
            for (int q = 0; q < 10; ++q) lv[q] = lp4[q];
            const float* lf = (const float*)lv;

            const float svA = epi_score(cAccA, cW2A, cWpA, cWgA, cPar, cGp, cB2A, quad);
            const float svB = epi_score(cAccB, cW2B, cWpB, cWgB, cPar, cGp, cB2B, quad);
            const float pA = 1.0f / (1.0f + __expf(-svA));
            const float pB = 1.0f / (1.0f + __expf(-svB));
            const float pLA = cPparA * pA, pRA = cPparA * (1.0f - pA);
            const float pLB = cPparB * pB, pRB = cPparB * (1.0f - pB);
            #pragma unroll
            for (int c = 0; c < NC; ++c)
                oacc[c] = fmaf(pLA, lf[c], fmaf(pRA, lf[NC + c], oacc[c]));
            #pragma unroll
            for (int c = 0; c < NC; ++c)
                oacc[c] = fmaf(pLB, lf[2 * NC + c], fmaf(pRB, lf[3 * NC + c], oacc[c]));
        }
    }

    // ---------------- cross-wave out reduction through scbuf ----------------
    __syncthreads();
    {
        float* red = &scbuf[0][0];         // 4*64*10 = 2560 floats <= 8128
        #pragma unroll
        for (int c = 0; c < NC; ++c)
            red[(wv * 64 + l) * NC + c] = oacc[c];
    }
    __syncthreads();
    {
        const float* red = &scbuf[0][0];
        for (int i = tid; i < TS * NC; i += BLOCK) {
            float v = red[i] + red[640 + i] + red[1280 + i] + red[1920 + i];
            out[(size_t)s0 * NC + i] = v;
        }
    }
}

} // namespace

extern "C" void kernel_launch(void* const* d_in, const int* in_sizes, int n_in,
                              void* d_out, int out_size, void* d_ws, size_t ws_size,
                              hipStream_t stream) {
    const float* x           = (const float*)d_in[0];
    const float* path_prob   = (const float*)d_in[1];
    const float* W1          = (const float*)d_in[2];
    const float* b1          = (const float*)d_in[3];
    const float* w2          = (const float*)d_in[4];
    const float* b2          = (const float*)d_in[5];
    const float* leaf_logits = (const float*)d_in[6];
    float* out = (float*)d_out;

    const int batch = in_sizes[0] / IN_DIM;                // 32768
    f16x8* wfrag = (f16x8*)d_ws;                           // 255*4*64*16B ~= 1.04 MB

    hipLaunchKernelGGL(prep_w1, dim3(NODES), dim3(256), 0, stream, W1, wfrag);
    hipLaunchKernelGGL(tree_mfma, dim3(batch / TS), dim3(BLOCK), 0, stream,
                       x, path_prob, W1, b1, w2, b2, leaf_logits, wfrag, out);
}